// Round 5
// baseline (38.038 us; speedup 1.0000x reference)
//
#include <hip/hip_runtime.h>

#define TPB   256
#define ROWS  4
#define RPB   (TPB * ROWS)      // rows per block = 1024
#define NWORD (RPB / 64)        // 16 mask words per block

__device__ __forceinline__ float pair_loss(float p0, float s0, float p1, float s1) {
    float dp = p0 - p1;
    float ds = s0 - s1;
    float sg = (ds > 0.0f) ? 1.0f : ((ds < 0.0f) ? -1.0f : 0.0f);
    float t  = dp * sg;
    // stable softplus(-t) = max(-t,0) + log1p(exp(-|t|))
    return fmaxf(-t, 0.0f) + log1pf(__expf(-fabsf(t)));
}

// Row's top softmax prob p and mask (argmax==0) from 16 logits.
__device__ __forceinline__ void row_stats(const float* __restrict__ outp, int row,
                                          float& p, bool& mask) {
    const float4* o4 = (const float4*)outp + (size_t)row * 4;
    float4 a = o4[0];
    float4 b = o4[1];
    float4 c = o4[2];
    float4 d = o4[3];
    float m01 = fmaxf(fmaxf(a.x, a.y), fmaxf(a.z, a.w));
    float m23 = fmaxf(fmaxf(b.x, b.y), fmaxf(b.z, b.w));
    float m45 = fmaxf(fmaxf(c.x, c.y), fmaxf(c.z, c.w));
    float m67 = fmaxf(fmaxf(d.x, d.y), fmaxf(d.z, d.w));
    float m = fmaxf(fmaxf(m01, m23), fmaxf(m45, m67));
    float sum = __expf(a.x - m) + __expf(a.y - m) + __expf(a.z - m) + __expf(a.w - m)
              + __expf(b.x - m) + __expf(b.y - m) + __expf(b.z - m) + __expf(b.w - m)
              + __expf(c.x - m) + __expf(c.y - m) + __expf(c.z - m) + __expf(c.w - m)
              + __expf(d.x - m) + __expf(d.y - m) + __expf(d.z - m) + __expf(d.w - m);
    p = __builtin_amdgcn_rcpf(sum);   // ~1ulp approx; tolerance is huge
    mask = (a.x == m);
}

// k1: 4 rows/thread. Block-local adjacent-selected pairs via block bitmask,
//     cross-boundary pair via forward scan, per-block partial write.
__global__ void __launch_bounds__(TPB) k_fused(const float* __restrict__ outp,
                                               const float* __restrict__ score,
                                               float* __restrict__ bpart, int B) {
    __shared__ float sp[RPB];
    __shared__ float ss[RPB];
    __shared__ unsigned char nib[TPB];
    __shared__ unsigned long long wmask[NWORD];
    __shared__ float wsum[TPB / 64];

    int tid  = threadIdx.x;
    int lane = tid & 63;
    int wid  = tid >> 6;
    int blk0 = blockIdx.x * RPB;
    int r0   = blk0 + tid * ROWS;

    float p[ROWS], sc[ROWS];
    bool  mk[ROWS];
    unsigned int mynib = 0;

    // scores: one aligned float4 per thread (coalesced), guarded for tail
    if (r0 + ROWS <= B) {
        float4 s4 = ((const float4*)score)[blk0 / 4 + tid];
        sc[0] = s4.x; sc[1] = s4.y; sc[2] = s4.z; sc[3] = s4.w;
    } else {
        for (int j = 0; j < ROWS; ++j) sc[j] = (r0 + j < B) ? score[r0 + j] : 0.0f;
    }
    for (int j = 0; j < ROWS; ++j) {
        p[j] = 0.0f; mk[j] = false;
        if (r0 + j < B) row_stats(outp, r0 + j, p[j], mk[j]);
        sp[tid * ROWS + j] = p[j];
        ss[tid * ROWS + j] = sc[j];
        if (mk[j]) mynib |= 1u << j;
    }
    nib[tid] = (unsigned char)mynib;
    __syncthreads();

    // assemble 1024-bit selected mask: word w <- nibbles of threads 16w..16w+15
    if (tid < NWORD) {
        unsigned long long w = 0;
        for (int k = 0; k < 16; ++k)
            w |= (unsigned long long)(nib[tid * 16 + k] & 0xF) << (4 * k);
        wmask[tid] = w;
    }
    __syncthreads();

    float acc = 0.0f;
    // block-local pairs: for each of my selected rows find next selected row
    for (int j = 0; j < ROWS; ++j) {
        if (!mk[j]) continue;
        int i  = tid * ROWS + j;          // row index within block
        int w0 = i >> 6, b0 = i & 63;
        unsigned long long above = wmask[w0] & ~((2ull << b0) - 1ull); // b0=63 -> 0-1 -> ~ -> 0
        int nxt = -1;
        if (above) {
            nxt = (w0 << 6) + __ffsll(above) - 1;
        } else {
            for (int w = w0 + 1; w < NWORD; ++w)
                if (wmask[w]) { nxt = (w << 6) + __ffsll(wmask[w]) - 1; break; }
        }
        if (nxt >= 0) acc += pair_loss(p[j], sc[j], sp[nxt], ss[nxt]);
    }

    // wave 0: cross-boundary pair via forward scan into following rows
    if (wid == 0) {
        int last = -1;
        for (int w = NWORD - 1; w >= 0; --w)
            if (wmask[w]) { last = (w << 6) + 63 - __clzll(wmask[w]); break; }
        if (last >= 0) {
            float pl = sp[last];
            float sl = ss[last];
            int base = blk0 + RPB;
            while (base < B) {
                int r = base + lane;
                bool sel = false;
                float pf = 0.0f, sf = 0.0f;
                if (r < B) {
                    row_stats(outp, r, pf, sel);
                    sf = score[r];
                }
                unsigned long long b2 = __ballot(sel);
                if (b2) {
                    int fl = __ffsll(b2) - 1;
                    float pfirst = __shfl(pf, fl);
                    float sfirst = __shfl(sf, fl);
                    if (lane == 0) acc += pair_loss(pl, sl, pfirst, sfirst);
                    break;
                }
                base += 64;
            }
        }
    }

    // block reduce -> contention-free partial
    for (int off = 32; off > 0; off >>= 1) acc += __shfl_down(acc, off);
    if (lane == 0) wsum[wid] = acc;
    __syncthreads();
    if (tid == 0)
        bpart[blockIdx.x] = wsum[0] + wsum[1] + wsum[2] + wsum[3];
}

// k2: single block sums the per-block partials, writes out[0].
__global__ void k2_sum(const float* __restrict__ bpart, int nb,
                       float* __restrict__ out) {
    __shared__ float wsum[16];
    float acc = 0.0f;
    for (int b = threadIdx.x; b < nb; b += 1024) acc += bpart[b];
    int lane = threadIdx.x & 63;
    int wid  = threadIdx.x >> 6;
    for (int off = 32; off > 0; off >>= 1) acc += __shfl_down(acc, off);
    if (lane == 0) wsum[wid] = acc;
    __syncthreads();
    if (threadIdx.x == 0) {
        float t = 0.0f;
        for (int w = 0; w < 16; ++w) t += wsum[w];
        out[0] = t;
    }
}

extern "C" void kernel_launch(void* const* d_in, const int* in_sizes, int n_in,
                              void* d_out, int out_size, void* d_ws, size_t ws_size,
                              hipStream_t stream) {
    const float* outp  = (const float*)d_in[0];   // [B,16] logits
    const float* score = (const float*)d_in[1];   // [B]
    float* out = (float*)d_out;

    int B  = in_sizes[1];
    int nb = (B + RPB - 1) / RPB;

    float* bpart = (float*)d_ws;

    k_fused<<<nb, TPB, 0, stream>>>(outp, score, bpart, B);
    k2_sum<<<1, 1024, 0, stream>>>(bpart, nb, out);
}

// Round 6
// 31.355 us; speedup vs baseline: 1.2131x; 1.2131x over previous
//
#include <hip/hip_runtime.h>

#define TPB 512
#define NW  (TPB / 64)   // 8 waves per block

__device__ __forceinline__ float pair_loss(float p0, float s0, float p1, float s1) {
    float dp = p0 - p1;
    float ds = s0 - s1;
    float sg = (ds > 0.0f) ? 1.0f : ((ds < 0.0f) ? -1.0f : 0.0f);
    float t  = dp * sg;
    // stable softplus(-t) = max(-t,0) + log1p(exp(-|t|))
    return fmaxf(-t, 0.0f) + log1pf(__expf(-fabsf(t)));
}

// Row's top softmax prob p and mask (argmax==0) from 16 logits.
__device__ __forceinline__ void row_stats(const float* __restrict__ outp, int row,
                                          float& p, bool& mask) {
    const float4* o4 = (const float4*)outp + (size_t)row * 4;
    float4 a = o4[0];
    float4 b = o4[1];
    float4 c = o4[2];
    float4 d = o4[3];
    float m01 = fmaxf(fmaxf(a.x, a.y), fmaxf(a.z, a.w));
    float m23 = fmaxf(fmaxf(b.x, b.y), fmaxf(b.z, b.w));
    float m45 = fmaxf(fmaxf(c.x, c.y), fmaxf(c.z, c.w));
    float m67 = fmaxf(fmaxf(d.x, d.y), fmaxf(d.z, d.w));
    float m = fmaxf(fmaxf(m01, m23), fmaxf(m45, m67));
    float sum = __expf(a.x - m) + __expf(a.y - m) + __expf(a.z - m) + __expf(a.w - m)
              + __expf(b.x - m) + __expf(b.y - m) + __expf(b.z - m) + __expf(b.w - m)
              + __expf(c.x - m) + __expf(c.y - m) + __expf(c.z - m) + __expf(c.w - m)
              + __expf(d.x - m) + __expf(d.y - m) + __expf(d.z - m) + __expf(d.w - m);
    p = __builtin_amdgcn_rcpf(sum);   // ~1ulp approx; tolerance is huge
    mask = (a.x == m);
}

// k1: 1 row/thread, 512-thread blocks. Block-local adjacent-selected pairs +
//     own cross-boundary pair via forward scan; per-block partial (no atomics).
__global__ void __launch_bounds__(TPB) k_fused(const float* __restrict__ outp,
                                               const float* __restrict__ score,
                                               float* __restrict__ bpart, int B) {
    __shared__ float sp[TPB];
    __shared__ float ss[TPB];
    __shared__ unsigned long long wmask[NW];
    __shared__ float wsum[NW];

    int tid  = threadIdx.x;
    int lane = tid & 63;
    int wid  = tid >> 6;
    int row  = blockIdx.x * TPB + tid;

    bool mask = false;
    float p = 0.0f, s = 0.0f;
    if (row < B) {
        row_stats(outp, row, p, mask);
        s = score[row];                // coalesced
    }
    sp[tid] = p;
    ss[tid] = s;

    unsigned long long bal = __ballot(mask);
    if (lane == 0) wmask[wid] = bal;
    __syncthreads();

    float acc = 0.0f;
    if (mask) {
        // next selected thread index within this block
        unsigned long long above = bal & ~((2ull << lane) - 1ull); // lane 63: (2<<63)==0 -> above=0
        int nxt = -1;
        if (above) {
            nxt = (wid << 6) + __ffsll(above) - 1;
        } else {
            for (int w = wid + 1; w < NW; ++w)
                if (wmask[w]) { nxt = (w << 6) + __ffsll(wmask[w]) - 1; break; }
        }
        if (nxt >= 0) acc = pair_loss(p, s, sp[nxt], ss[nxt]);
    }

    // wave 0: cross-boundary pair via forward scan into following rows
    // (runs concurrently with other waves' pair loop above)
    if (wid == 0) {
        int last = -1;
        for (int w = NW - 1; w >= 0; --w)
            if (wmask[w]) { last = (w << 6) + 63 - __clzll(wmask[w]); break; }
        if (last >= 0) {
            float pl = sp[last];
            float sl = ss[last];
            int base = (blockIdx.x + 1) * TPB;
            while (base < B) {
                int r = base + lane;
                bool sel = false;
                float pf = 0.0f, sf = 0.0f;
                if (r < B) {
                    row_stats(outp, r, pf, sel);
                    sf = score[r];
                }
                unsigned long long b2 = __ballot(sel);
                if (b2) {
                    int fl = __ffsll(b2) - 1;
                    float pfirst = __shfl(pf, fl);
                    float sfirst = __shfl(sf, fl);
                    if (lane == 0) acc += pair_loss(pl, sl, pfirst, sfirst);
                    break;
                }
                base += 64;
            }
        }
    }

    // block reduce -> contention-free partial write
    for (int off = 32; off > 0; off >>= 1) acc += __shfl_down(acc, off);
    if (lane == 0) wsum[wid] = acc;
    __syncthreads();
    if (tid == 0) {
        float t = 0.0f;
        for (int w = 0; w < NW; ++w) t += wsum[w];
        bpart[blockIdx.x] = t;
    }
}

// k2: single block sums the per-block partials, writes out[0].
__global__ void k2_sum(const float* __restrict__ bpart, int nb,
                       float* __restrict__ out) {
    __shared__ float wsum[16];
    float acc = 0.0f;
    for (int b = threadIdx.x; b < nb; b += 1024) acc += bpart[b];
    int lane = threadIdx.x & 63;
    int wid  = threadIdx.x >> 6;
    for (int off = 32; off > 0; off >>= 1) acc += __shfl_down(acc, off);
    if (lane == 0) wsum[wid] = acc;
    __syncthreads();
    if (threadIdx.x == 0) {
        float t = 0.0f;
        for (int w = 0; w < 16; ++w) t += wsum[w];
        out[0] = t;
    }
}

extern "C" void kernel_launch(void* const* d_in, const int* in_sizes, int n_in,
                              void* d_out, int out_size, void* d_ws, size_t ws_size,
                              hipStream_t stream) {
    const float* outp  = (const float*)d_in[0];   // [B,16] logits
    const float* score = (const float*)d_in[1];   // [B]
    float* out = (float*)d_out;

    int B  = in_sizes[1];
    int nb = (B + TPB - 1) / TPB;

    float* bpart = (float*)d_ws;

    k_fused<<<nb, TPB, 0, stream>>>(outp, score, bpart, B);
    k2_sum<<<1, 1024, 0, stream>>>(bpart, nb, out);
}